// Round 3
// baseline (703.530 us; speedup 1.0000x reference)
//
#include <hip/hip_runtime.h>
#include <math.h>

#define NB 64
#define NT 512
#define ND 768
#define NK 29
#define L2E 1.4426950408889634f
#define LN2 0.6931471805599453f
#define NEG_BIG -1e30f

__device__ __forceinline__ float rdlane(float v, int i) {
    return __int_as_float(__builtin_amdgcn_readlane(__float_as_int(v), i));
}

// ---------------------------------------------------------------------------
// Kernel 1: emissions  em[tok][k] = dot(emb[x[tok]], w[k]) + b[k]
// 512 blocks x 128 thr = 1024 waves. wave = 32 tokens x all 29 k.
// Lane pair (2 lanes/token): even lane k 0..14, odd lane k 15..28 -> emb row
// gathered exactly once (98 MB total). e rows staged per-wave in LDS in
// 32-float d-tiles (in-wave DS ordering, no barriers); w via broadcast loads.
// Accumulation d-order/expression identical to R2 per (token,k).
// ---------------------------------------------------------------------------
template<int KN>
__device__ __forceinline__ void emis_wave(
    const float* __restrict__ erowp, const float* __restrict__ w,
    const float* __restrict__ bias, float* __restrict__ em,
    float* eb, int tok, int kbase, int r, int h2)
{
    float acc[KN];
#pragma unroll
    for (int k = 0; k < KN; ++k) acc[k] = 0.f;

    const float* myrow = eb + r * 36;

    for (int tile = 0; tile < 24; ++tile) {
        // stage own half-row: 4 float4s (cols h2*16 + 0..15 of this 32-tile)
#pragma unroll
        for (int i = 0; i < 4; ++i) {
            float4 v = *(const float4*)(erowp + tile * 32 + h2 * 16 + 4 * i);
            *(float4*)(eb + r * 36 + h2 * 16 + 4 * i) = v;
        }
        // in-wave DS ordering: reads below see writes above (single wave)
        float4 ereg[8];
#pragma unroll
        for (int c = 0; c < 8; ++c) ereg[c] = *(const float4*)(myrow + 4 * c);

#pragma unroll
        for (int k = 0; k < KN; ++k) {
            const float* wr = w + (size_t)(kbase + k) * ND + tile * 32;
#pragma unroll
            for (int c = 0; c < 8; ++c) {
                float4 w4 = *(const float4*)(wr + 4 * c);
                acc[k] += ereg[c].x * w4.x + ereg[c].y * w4.y
                        + ereg[c].z * w4.z + ereg[c].w * w4.w;
            }
        }
    }
#pragma unroll
    for (int k = 0; k < KN; ++k)
        em[(size_t)tok * NK + kbase + k] = acc[k] + bias[kbase + k];
}

__global__ __launch_bounds__(128) void k_emissions(
    const int* __restrict__ x, const float* __restrict__ emb,
    const float* __restrict__ w, const float* __restrict__ bias,
    float* __restrict__ em)
{
    __shared__ __align__(16) float elds[2][32 * 36];   // 9216 B
    const int wv = threadIdx.x >> 6;
    const int lane = threadIdx.x & 63;
    const int wave_id = blockIdx.x * 2 + wv;           // 0..1023
    const int tokbase = wave_id * 32;
    const int r = lane >> 1;                            // token row in wave
    const int h2 = lane & 1;                            // row half / k half
    const int tok = tokbase + r;
    const float* erowp = emb + (size_t)x[tok] * ND;
    if (h2 == 0) emis_wave<15>(erowp, w, bias, em, elds[wv], tok, 0, r, 0);
    else         emis_wave<14>(erowp, w, bias, em, elds[wv], tok, 15, r, 1);
}

// ---------------------------------------------------------------------------
// Kernel 2: scans. blocks 0..63 CRF forward, 64..127 Viterbi. 64 thr = 1 wave.
// Broadcast of the state vector via v_readlane (no LDS round-trip / shfl on
// the per-step chain). CRF: scaled exp domain, 2^-5/step constant rescale +
// exact pow2 correction every 16 steps via readfirstlane.
// Viterbi: (val,idx) tournament (first-max semantics, matches argmax),
// parallel segmented backtrace.
// ---------------------------------------------------------------------------
__global__ __launch_bounds__(64) void k_scan(
    const float* __restrict__ em, const int* __restrict__ tags,
    const float* __restrict__ st, const float* __restrict__ en,
    const float* __restrict__ tr, float* __restrict__ part,
    float* __restrict__ out)
{
    __shared__ __align__(16) unsigned char smem[NT * NK * 4];
    const int lane = threadIdx.x;
    const int jc = (lane < NK) ? lane : NK - 1;

    if (blockIdx.x < NB) {
        // ----------------- CRF forward (scaled exp domain, readlane) -------
        const int b = blockIdx.x;
        float* emS = (float*)smem;                     // [512][29]
        {
            const float4* src = (const float4*)(em + (size_t)b * NT * NK);
            float4* dst = (float4*)emS;
            for (int i = lane; i < NT * NK / 4; i += 64) dst[i] = src[i];
        }
        float EC[NK];
#pragma unroll
        for (int i = 0; i < NK; ++i) EC[i] = __expf(tr[i * NK + jc]);

        float a = __expf(st[jc] + emS[jc]);            // lane j holds a_j
        int eshift = 5 * (NT - 1);
        float eemc = exp2f(fmaf(emS[NK + jc], L2E, -5.0f));
        float rawn = emS[2 * NK + jc];

        for (int t = 1; t < NT; ++t) {
            float p0 = 0.f, p1 = 0.f, p2 = 0.f, p3 = 0.f;
#pragma unroll
            for (int i = 0; i < NK; ++i) {
                float si = rdlane(a, i);
                if ((i & 3) == 0)      p0 = fmaf(si, EC[i], p0);
                else if ((i & 3) == 1) p1 = fmaf(si, EC[i], p1);
                else if ((i & 3) == 2) p2 = fmaf(si, EC[i], p2);
                else                   p3 = fmaf(si, EC[i], p3);
            }
            float anew = ((p0 + p1) + (p2 + p3)) * eemc;
            // refill eem pipeline (off critical chain)
            eemc = exp2f(fmaf(rawn, L2E, -5.0f));
            int tn = t + 2; tn = tn < NT ? tn : NT - 1;
            rawn = emS[tn * NK + jc];

            if ((t & 15) == 0) {       // exact pow2 renorm via lane-0 probe
                unsigned mb = (unsigned)__builtin_amdgcn_readfirstlane(
                                  __float_as_int(anew));
                int ex = (int)((mb >> 23) & 255u) - 127;
                anew *= __int_as_float((unsigned)(127 - ex) << 23);
                eshift += ex;
            }
            a = anew;
        }
        // logZ = log(sum_j a_j * exp(en_j)) + eshift*ln2
        float val = (lane < NK) ? a * __expf(en[jc]) : 0.f;
#pragma unroll
        for (int s = 32; s; s >>= 1) val += __shfl_xor(val, s);
        float logZ = logf(val) + (float)eshift * LN2;
        // numerator (exact)
        const int* tg = tags + b * NT;
        float p = 0.f;
        for (int t = lane; t < NT; t += 64) {
            int tt = tg[t];
            p += emS[t * NK + tt];
            if (t == 0) p += st[tt];
            else        p += tr[tg[t - 1] * NK + tt];
            if (t == NT - 1) p += en[tt];
        }
#pragma unroll
        for (int s = 32; s; s >>= 1) p += __shfl_xor(p, s);
        if (lane == 0) part[b] = logZ - p;
    } else {
        // ----------------- Viterbi (readlane) + parallel backtrace ---------
        const int b = blockIdx.x - NB;
        const float* emb_b = em + (size_t)b * NT * NK;
        unsigned char* sbp = smem;                     // [511][32]
        unsigned char* smap = smem + 511 * 32;         // [16][32]

        float Tc[NK];
#pragma unroll
        for (int i = 0; i < NK; ++i) Tc[i] = tr[i * NK + jc];

        float sc = (lane < NK) ? (st[jc] + emb_b[jc]) : NEG_BIG;

        float e0 = emb_b[1 * NK + jc];
        float e1 = emb_b[2 * NK + jc];
        float e2 = emb_b[3 * NK + jc];
        float e3 = emb_b[4 * NK + jc];

        auto vstep = [&](int t, float emt) {
            float v[32]; int id[32];
#pragma unroll
            for (int i = 0; i < NK; ++i) {
                v[i] = rdlane(sc, i) + Tc[i];
                id[i] = i;
            }
#pragma unroll
            for (int i = NK; i < 32; ++i) { v[i] = -3.0e38f; id[i] = 0; }
            // stable-left tournament => first-max (matches argmax)
#pragma unroll
            for (int w2 = 16; w2 >= 1; w2 >>= 1)
#pragma unroll
                for (int i = 0; i < 16; ++i) {
                    if (i < w2) {
                        bool g = v[i + w2] > v[i];
                        v[i] = g ? v[i + w2] : v[i];
                        id[i] = g ? id[i + w2] : id[i];
                    }
                }
            if (lane < 32) sbp[(t - 1) * 32 + lane] = (unsigned char)id[0];
            sc = (lane < NK) ? (v[0] + emt) : NEG_BIG;
        };

        int t = 1;
        for (; t + 3 < NT; t += 4) {
            vstep(t + 0, e0); { int tn = t + 4; tn = tn < NT ? tn : NT - 1; e0 = emb_b[tn * NK + jc]; }
            vstep(t + 1, e1); { int tn = t + 5; tn = tn < NT ? tn : NT - 1; e1 = emb_b[tn * NK + jc]; }
            vstep(t + 2, e2); { int tn = t + 6; tn = tn < NT ? tn : NT - 1; e2 = emb_b[tn * NK + jc]; }
            vstep(t + 3, e3); { int tn = t + 7; tn = tn < NT ? tn : NT - 1; e3 = emb_b[tn * NK + jc]; }
        }
        vstep(509, e0); vstep(510, e1); vstep(511, e2);

        // final tag
        float v = (lane < NK) ? (sc + en[jc]) : NEG_BIG;
        float M = v;
#pragma unroll
        for (int s = 32; s; s >>= 1) M = fmaxf(M, __shfl_xor(M, s));
        unsigned long long mk = __ballot((lane < NK) && v == M);
        int last = (int)__builtin_ctzll(mk);

        // ---- parallel backtrace: 16 segment maps of 32 rows ----
        const int h = lane >> 5, j5 = lane & 31;
        int cur8[8];
#pragma unroll
        for (int rep = 0; rep < 8; ++rep) cur8[rep] = j5;
        for (int off = 0; off < 32; ++off) {
#pragma unroll
            for (int rep = 0; rep < 8; ++rep) {
                int s = 2 * rep + h;
                int hi = (s == 15) ? 511 : 32 * s + 32;
                int r = hi - 1 - off;
                if (r >= 32 * s) cur8[rep] = sbp[r * 32 + cur8[rep]];
            }
        }
#pragma unroll
        for (int rep = 0; rep < 8; ++rep)
            smap[(2 * rep + h) * 32 + j5] = (unsigned char)cur8[rep];

        // boundary walk (uniform, all lanes; lane s snapshots its hi-tag)
        int myhi = 0, cur = last;
        for (int s = 15; s >= 0; --s) {
            if (lane == s) myhi = cur;
            cur = smap[s * 32 + cur];
        }
        // refill + write decoded
        float* op = out + 1 + (size_t)b * NT;
        if (lane == 16) op[NT - 1] = (float)last;
        if (lane < 16) {
            int s = lane;
            int hi = (s == 15) ? 511 : 32 * s + 32;
            int c = myhi;
            for (int r = hi - 1; r >= 32 * s; --r) {
                c = sbp[r * 32 + c];
                op[r] = (float)c;
            }
        }
    }
}

// ---------------------------------------------------------------------------
// Kernel 3: nll = sum_b (logZ_b - num_b)
// ---------------------------------------------------------------------------
__global__ __launch_bounds__(64) void k_finish(const float* __restrict__ part,
                                               float* __restrict__ out)
{
    float v = part[threadIdx.x];
#pragma unroll
    for (int s = 32; s; s >>= 1) v += __shfl_xor(v, s);
    if (threadIdx.x == 0) out[0] = v;
}

extern "C" void kernel_launch(void* const* d_in, const int* in_sizes, int n_in,
                              void* d_out, int out_size, void* d_ws, size_t ws_size,
                              hipStream_t stream) {
    const int*   x    = (const int*)d_in[0];
    const int*   tags = (const int*)d_in[1];
    const float* emb  = (const float*)d_in[2];
    const float* w    = (const float*)d_in[3];
    const float* bias = (const float*)d_in[4];
    const float* st   = (const float*)d_in[5];
    const float* en   = (const float*)d_in[6];
    const float* tr   = (const float*)d_in[7];
    float* out = (float*)d_out;

    float* em   = (float*)d_ws;                                     // B*T*K
    float* part = (float*)((char*)d_ws + (size_t)NB * NT * NK * 4); // B floats

    k_emissions<<<512, 128, 0, stream>>>(x, emb, w, bias, em);
    k_scan<<<2 * NB, 64, 0, stream>>>(em, tags, st, en, tr, part, out);
    k_finish<<<1, 64, 0, stream>>>(part, out);
}

// Round 5
// 525.165 us; speedup vs baseline: 1.3396x; 1.3396x over previous
//
#include <hip/hip_runtime.h>
#include <math.h>

#define NB 64
#define NT 512
#define ND 768
#define NK 29
#define L2E 1.4426950408889634f
#define LN2 0.6931471805599453f
#define NEG_BIG -1e30f

__device__ __forceinline__ float rdlane(float v, int i) {
    return __int_as_float(__builtin_amdgcn_readlane(__float_as_int(v), i));
}

// ---------------------------------------------------------------------------
// Kernel 1: emissions  em[tok][k] = dot(emb[x[tok]], w[k]) + b[k]
// 512 blocks x 128 thr (2 waves). Block = 64 tokens; wave = d-half (384).
// lane = token: e streamed from global into VGPRs (prefetch distance 1 chunk,
// address clamped on the last chunk -> no uninitialized regs).
// w accessed at wave-uniform addresses (wvu via readfirstlane) -> scalar
// s_load through the constant cache: no vector-load latency chains, no LDS
// traffic in the main loop. Cross-wave d-reduction via padded LDS.
// ---------------------------------------------------------------------------
__global__ __launch_bounds__(128, 2) void k_emissions(
    const int* __restrict__ x, const float* __restrict__ emb,
    const float* __restrict__ w, const float* __restrict__ bias,
    float* __restrict__ em)
{
    __shared__ float red[64 * 33];                     // 8448 B
    const int lane = threadIdx.x & 63;
    const int wvu = __builtin_amdgcn_readfirstlane(threadIdx.x >> 6); // d-half
    const int tok = blockIdx.x * 64 + lane;
    const float* row = emb + (size_t)x[tok] * ND + wvu * 384;

    float acc[NK];
#pragma unroll
    for (int k = 0; k < NK; ++k) acc[k] = 0.f;

    float4 e0 = ((const float4*)row)[0];
    float4 e1 = ((const float4*)row)[1];
    float4 e2 = ((const float4*)row)[2];
    float4 e3 = ((const float4*)row)[3];

    for (int c = 0; c < 24; ++c) {
        // prefetch next chunk (clamped address on last iter; values unused)
        int cn = (c < 23) ? (c + 1) : 23;
        const float4* nr = (const float4*)(row + cn * 16);
        float4 n0 = nr[0], n1 = nr[1], n2 = nr[2], n3 = nr[3];

        const float* wbase = w + wvu * 384 + c * 16;   // wave-uniform
#pragma unroll
        for (int k = 0; k < NK; ++k) {
            const float* wr = wbase + k * ND;          // -> s_load
            acc[k] += e0.x * wr[0]  + e0.y * wr[1]  + e0.z * wr[2]  + e0.w * wr[3]
                    + e1.x * wr[4]  + e1.y * wr[5]  + e1.z * wr[6]  + e1.w * wr[7]
                    + e2.x * wr[8]  + e2.y * wr[9]  + e2.z * wr[10] + e2.w * wr[11]
                    + e3.x * wr[12] + e3.y * wr[13] + e3.z * wr[14] + e3.w * wr[15];
        }
        e0 = n0; e1 = n1; e2 = n2; e3 = n3;
    }

    if (wvu == 0) {
#pragma unroll
        for (int k = 0; k < NK; ++k) red[lane * 33 + k] = acc[k];
    }
    __syncthreads();
    if (wvu == 1) {
#pragma unroll
        for (int k = 0; k < NK; ++k)
            red[lane * 33 + k] += acc[k] + bias[k];
    }
    __syncthreads();
    float* dst = em + (size_t)blockIdx.x * 64 * NK;
    for (int i = threadIdx.x; i < 64 * NK; i += 128) {
        int t = i / NK, k = i - t * NK;
        dst[i] = red[t * 33 + k];
    }
}

// ---------------------------------------------------------------------------
// Kernel 2: scans. blocks 0..63 CRF forward, 64..127 Viterbi. 64 thr = 1 wave.
// (unchanged from R3)
// ---------------------------------------------------------------------------
__global__ __launch_bounds__(64) void k_scan(
    const float* __restrict__ em, const int* __restrict__ tags,
    const float* __restrict__ st, const float* __restrict__ en,
    const float* __restrict__ tr, float* __restrict__ part,
    float* __restrict__ out)
{
    __shared__ __align__(16) unsigned char smem[NT * NK * 4];
    const int lane = threadIdx.x;
    const int jc = (lane < NK) ? lane : NK - 1;

    if (blockIdx.x < NB) {
        // ----------------- CRF forward (scaled exp domain, readlane) -------
        const int b = blockIdx.x;
        float* emS = (float*)smem;                     // [512][29]
        {
            const float4* src = (const float4*)(em + (size_t)b * NT * NK);
            float4* dst = (float4*)emS;
            for (int i = lane; i < NT * NK / 4; i += 64) dst[i] = src[i];
        }
        float EC[NK];
#pragma unroll
        for (int i = 0; i < NK; ++i) EC[i] = __expf(tr[i * NK + jc]);

        float a = __expf(st[jc] + emS[jc]);            // lane j holds a_j
        int eshift = 5 * (NT - 1);
        float eemc = exp2f(fmaf(emS[NK + jc], L2E, -5.0f));
        float rawn = emS[2 * NK + jc];

        for (int t = 1; t < NT; ++t) {
            float p0 = 0.f, p1 = 0.f, p2 = 0.f, p3 = 0.f;
#pragma unroll
            for (int i = 0; i < NK; ++i) {
                float si = rdlane(a, i);
                if ((i & 3) == 0)      p0 = fmaf(si, EC[i], p0);
                else if ((i & 3) == 1) p1 = fmaf(si, EC[i], p1);
                else if ((i & 3) == 2) p2 = fmaf(si, EC[i], p2);
                else                   p3 = fmaf(si, EC[i], p3);
            }
            float anew = ((p0 + p1) + (p2 + p3)) * eemc;
            eemc = exp2f(fmaf(rawn, L2E, -5.0f));
            int tn = t + 2; tn = tn < NT ? tn : NT - 1;
            rawn = emS[tn * NK + jc];

            if ((t & 15) == 0) {       // exact pow2 renorm via lane-0 probe
                unsigned mb = (unsigned)__builtin_amdgcn_readfirstlane(
                                  __float_as_int(anew));
                int ex = (int)((mb >> 23) & 255u) - 127;
                anew *= __int_as_float((unsigned)(127 - ex) << 23);
                eshift += ex;
            }
            a = anew;
        }
        float val = (lane < NK) ? a * __expf(en[jc]) : 0.f;
#pragma unroll
        for (int s = 32; s; s >>= 1) val += __shfl_xor(val, s);
        float logZ = logf(val) + (float)eshift * LN2;
        const int* tg = tags + b * NT;
        float p = 0.f;
        for (int t = lane; t < NT; t += 64) {
            int tt = tg[t];
            p += emS[t * NK + tt];
            if (t == 0) p += st[tt];
            else        p += tr[tg[t - 1] * NK + tt];
            if (t == NT - 1) p += en[tt];
        }
#pragma unroll
        for (int s = 32; s; s >>= 1) p += __shfl_xor(p, s);
        if (lane == 0) part[b] = logZ - p;
    } else {
        // ----------------- Viterbi (readlane) + parallel backtrace ---------
        const int b = blockIdx.x - NB;
        const float* emb_b = em + (size_t)b * NT * NK;
        unsigned char* sbp = smem;                     // [511][32]
        unsigned char* smap = smem + 511 * 32;         // [16][32]

        float Tc[NK];
#pragma unroll
        for (int i = 0; i < NK; ++i) Tc[i] = tr[i * NK + jc];

        float sc = (lane < NK) ? (st[jc] + emb_b[jc]) : NEG_BIG;

        float e0 = emb_b[1 * NK + jc];
        float e1 = emb_b[2 * NK + jc];
        float e2 = emb_b[3 * NK + jc];
        float e3 = emb_b[4 * NK + jc];

        auto vstep = [&](int t, float emt) {
            float v[32]; int id[32];
#pragma unroll
            for (int i = 0; i < NK; ++i) {
                v[i] = rdlane(sc, i) + Tc[i];
                id[i] = i;
            }
#pragma unroll
            for (int i = NK; i < 32; ++i) { v[i] = -3.0e38f; id[i] = 0; }
#pragma unroll
            for (int w2 = 16; w2 >= 1; w2 >>= 1)
#pragma unroll
                for (int i = 0; i < 16; ++i) {
                    if (i < w2) {
                        bool g = v[i + w2] > v[i];
                        v[i] = g ? v[i + w2] : v[i];
                        id[i] = g ? id[i + w2] : id[i];
                    }
                }
            if (lane < 32) sbp[(t - 1) * 32 + lane] = (unsigned char)id[0];
            sc = (lane < NK) ? (v[0] + emt) : NEG_BIG;
        };

        int t = 1;
        for (; t + 3 < NT; t += 4) {
            vstep(t + 0, e0); { int tn = t + 4; tn = tn < NT ? tn : NT - 1; e0 = emb_b[tn * NK + jc]; }
            vstep(t + 1, e1); { int tn = t + 5; tn = tn < NT ? tn : NT - 1; e1 = emb_b[tn * NK + jc]; }
            vstep(t + 2, e2); { int tn = t + 6; tn = tn < NT ? tn : NT - 1; e2 = emb_b[tn * NK + jc]; }
            vstep(t + 3, e3); { int tn = t + 7; tn = tn < NT ? tn : NT - 1; e3 = emb_b[tn * NK + jc]; }
        }
        vstep(509, e0); vstep(510, e1); vstep(511, e2);

        float v = (lane < NK) ? (sc + en[jc]) : NEG_BIG;
        float M = v;
#pragma unroll
        for (int s = 32; s; s >>= 1) M = fmaxf(M, __shfl_xor(M, s));
        unsigned long long mk = __ballot((lane < NK) && v == M);
        int last = (int)__builtin_ctzll(mk);

        const int h = lane >> 5, j5 = lane & 31;
        int cur8[8];
#pragma unroll
        for (int rep = 0; rep < 8; ++rep) cur8[rep] = j5;
        for (int off = 0; off < 32; ++off) {
#pragma unroll
            for (int rep = 0; rep < 8; ++rep) {
                int s = 2 * rep + h;
                int hi = (s == 15) ? 511 : 32 * s + 32;
                int r = hi - 1 - off;
                if (r >= 32 * s) cur8[rep] = sbp[r * 32 + cur8[rep]];
            }
        }
#pragma unroll
        for (int rep = 0; rep < 8; ++rep)
            smap[(2 * rep + h) * 32 + j5] = (unsigned char)cur8[rep];

        int myhi = 0, cur = last;
        for (int s = 15; s >= 0; --s) {
            if (lane == s) myhi = cur;
            cur = smap[s * 32 + cur];
        }
        float* op = out + 1 + (size_t)b * NT;
        if (lane == 16) op[NT - 1] = (float)last;
        if (lane < 16) {
            int s = lane;
            int hi = (s == 15) ? 511 : 32 * s + 32;
            int c = myhi;
            for (int r = hi - 1; r >= 32 * s; --r) {
                c = sbp[r * 32 + c];
                op[r] = (float)c;
            }
        }
    }
}

// ---------------------------------------------------------------------------
// Kernel 3: nll = sum_b (logZ_b - num_b)
// ---------------------------------------------------------------------------
__global__ __launch_bounds__(64) void k_finish(const float* __restrict__ part,
                                               float* __restrict__ out)
{
    float v = part[threadIdx.x];
#pragma unroll
    for (int s = 32; s; s >>= 1) v += __shfl_xor(v, s);
    if (threadIdx.x == 0) out[0] = v;
}

extern "C" void kernel_launch(void* const* d_in, const int* in_sizes, int n_in,
                              void* d_out, int out_size, void* d_ws, size_t ws_size,
                              hipStream_t stream) {
    const int*   x    = (const int*)d_in[0];
    const int*   tags = (const int*)d_in[1];
    const float* emb  = (const float*)d_in[2];
    const float* w    = (const float*)d_in[3];
    const float* bias = (const float*)d_in[4];
    const float* st   = (const float*)d_in[5];
    const float* en   = (const float*)d_in[6];
    const float* tr   = (const float*)d_in[7];
    float* out = (float*)d_out;

    float* em   = (float*)d_ws;                                     // B*T*K
    float* part = (float*)((char*)d_ws + (size_t)NB * NT * NK * 4); // B floats

    k_emissions<<<512, 128, 0, stream>>>(x, emb, w, bias, em);
    k_scan<<<2 * NB, 64, 0, stream>>>(em, tags, st, en, tr, part, out);
    k_finish<<<1, 64, 0, stream>>>(part, out);
}

// Round 6
// 349.360 us; speedup vs baseline: 2.0138x; 1.5032x over previous
//
#include <hip/hip_runtime.h>
#include <math.h>

#define NB 64
#define NT 512
#define ND 768
#define NK 29
#define L2E 1.4426950408889634f
#define LN2 0.6931471805599453f
#define NEG_BIG -1e30f

typedef __attribute__((ext_vector_type(8))) short short8;
typedef __attribute__((ext_vector_type(4))) float floatx4;

__device__ __forceinline__ short bf16r(float f) {   // round-to-nearest-even
    unsigned u = __float_as_uint(f);
    unsigned r = (u + 0x7FFFu + ((u >> 16) & 1u)) >> 16;
    return (short)r;
}

// ---------------------------------------------------------------------------
// Kernel 0: convert w (29x768 fp32) -> wbf (32x768 bf16, rows 29..31 zero)
// ---------------------------------------------------------------------------
__global__ __launch_bounds__(256) void k_prep(const float* __restrict__ w,
                                              short* __restrict__ wbf)
{
    int i = blockIdx.x * 256 + threadIdx.x;            // 32*768 = 24576
    if (i < 32 * ND) {
        int row = i / ND;
        wbf[i] = (row < NK) ? bf16r(w[i]) : (short)0;
    }
}

// ---------------------------------------------------------------------------
// Kernel 1: emissions via bf16 MFMA.  em[tok][k] = dot(emb[x[tok]], w[k]) + b[k]
// 2048 blocks x 128 thr (2 waves). Block = 16 tokens (one M-tile), N = 32
// (two 16-col n-tiles, cols 29..31 dead), K = 768 split across the 2 waves.
// A-frag: lane reads 8 consecutive fp32 of its token row, packs to bf16.
// B-frag: 16B bf16x8 from wbf (L1/L2-hot, 45 KB total).
// Cross-wave reduce in LDS, then store with bias.
// ---------------------------------------------------------------------------
__global__ __launch_bounds__(128) void k_emissions(
    const int* __restrict__ x, const float* __restrict__ emb,
    const short* __restrict__ wbf, const float* __restrict__ bias,
    float* __restrict__ em)
{
    __shared__ float red[2 * 256];                     // wave1 partials
    const int lane = threadIdx.x & 63;
    const int wv = threadIdx.x >> 6;                   // d-half (0/1)
    const int col = lane & 15;                         // m for A, n for B
    const int quad = lane >> 4;                        // k-subrange selector
    const int Mbase = blockIdx.x * 16;
    const int tok = Mbase + col;

    const float* arow = emb + (size_t)x[tok] * ND + wv * 384 + quad * 8;
    const short* brow0 = wbf + (size_t)col * ND + wv * 384 + quad * 8;
    const short* brow1 = brow0 + 16 * ND;

    floatx4 acc0 = {0.f, 0.f, 0.f, 0.f};
    floatx4 acc1 = {0.f, 0.f, 0.f, 0.f};

    // pipeline: A prefetch distance 2 (HBM), B distance 1 (cache-hot)
    float4 a0  = *(const float4*)(arow);
    float4 a0b = *(const float4*)(arow + 4);
    float4 a1  = *(const float4*)(arow + 32);
    float4 a1b = *(const float4*)(arow + 36);
    short8 b0  = *(const short8*)(brow0);
    short8 b1  = *(const short8*)(brow1);

    for (int c = 0; c < 12; ++c) {
        int c2 = (c + 2 <= 11) ? c + 2 : 11;           // clamped prefetch
        float4 n0  = *(const float4*)(arow + c2 * 32);
        float4 n0b = *(const float4*)(arow + c2 * 32 + 4);
        int c1 = (c + 1 <= 11) ? c + 1 : 11;
        short8 nb0 = *(const short8*)(brow0 + c1 * 32);
        short8 nb1 = *(const short8*)(brow1 + c1 * 32);

        short8 af;
        af[0] = bf16r(a0.x);  af[1] = bf16r(a0.y);
        af[2] = bf16r(a0.z);  af[3] = bf16r(a0.w);
        af[4] = bf16r(a0b.x); af[5] = bf16r(a0b.y);
        af[6] = bf16r(a0b.z); af[7] = bf16r(a0b.w);

        acc0 = __builtin_amdgcn_mfma_f32_16x16x32_bf16(af, b0, acc0, 0, 0, 0);
        acc1 = __builtin_amdgcn_mfma_f32_16x16x32_bf16(af, b1, acc1, 0, 0, 0);

        a0 = a1; a0b = a1b; a1 = n0; a1b = n0b;
        b0 = nb0; b1 = nb1;
    }

    // reduce the two d-halves; C/D layout: row = quad*4+reg, col = lane&15
    const int r0 = quad * 4;
    if (wv == 1) {
#pragma unroll
        for (int reg = 0; reg < 4; ++reg) {
            red[(r0 + reg) * 16 + col]       = acc0[reg];
            red[256 + (r0 + reg) * 16 + col] = acc1[reg];
        }
    }
    __syncthreads();
    if (wv == 0) {
        float bs0 = bias[col];
        float bs1 = (col < NK - 16) ? bias[16 + col] : 0.f;
#pragma unroll
        for (int reg = 0; reg < 4; ++reg) {
            int row = r0 + reg;
            float v0 = acc0[reg] + red[row * 16 + col] + bs0;
            em[(size_t)(Mbase + row) * NK + col] = v0;
            if (col < NK - 16) {
                float v1 = acc1[reg] + red[256 + row * 16 + col] + bs1;
                em[(size_t)(Mbase + row) * NK + 16 + col] = v1;
            }
        }
    }
}

// ---------------------------------------------------------------------------
// Kernel 2: scans. blocks 0..63 CRF forward, 64..127 Viterbi. 64 thr = 1 wave
// => barrier-free (in-order DS pipe within a wave). State broadcast via
// uniform-address ds_read_b128 (LDS broadcast, conflict-free).
// CRF: scaled exp domain (R5 arithmetic). Viterbi: R5 tournament arithmetic.
// ---------------------------------------------------------------------------
__global__ __launch_bounds__(64) void k_scan(
    const float* __restrict__ em, const int* __restrict__ tags,
    const float* __restrict__ st, const float* __restrict__ en,
    const float* __restrict__ tr, float* __restrict__ part,
    float* __restrict__ out)
{
    __shared__ __align__(16) float sA[32];
    __shared__ __align__(16) unsigned char smem[NT * NK * 4];
    const float4* sA4 = (const float4*)sA;
    const int lane = threadIdx.x;
    const int jc = (lane < NK) ? lane : NK - 1;

    if (blockIdx.x < NB) {
        // ----------------- CRF forward (scaled exp domain) -----------------
        const int b = blockIdx.x;
        float* emS = (float*)smem;                     // [512][29]
        {
            const float4* src = (const float4*)(em + (size_t)b * NT * NK);
            float4* dst = (float4*)emS;
            for (int i = lane; i < NT * NK / 4; i += 64) dst[i] = src[i];
        }
        float EC[32];
#pragma unroll
        for (int i = 0; i < NK; ++i) EC[i] = __expf(tr[i * NK + jc]);
#pragma unroll
        for (int i = NK; i < 32; ++i) EC[i] = 0.f;

        float a0v = __expf(st[jc] + emS[jc]);
        if (lane < 32) sA[lane] = (lane < NK) ? a0v : 0.f;

        int eshift = 5 * (NT - 1);
        float eemc = exp2f(fmaf(emS[NK + jc], L2E, -5.0f));
        float rawn = emS[2 * NK + jc];
        float anew = a0v;

        for (int t = 1; t < NT; ++t) {
            float4 A[8];
#pragma unroll
            for (int ii = 0; ii < 8; ++ii) A[ii] = sA4[ii];   // broadcast reads
            float p0 = 0.f, p1 = 0.f, p2 = 0.f, p3 = 0.f;
#pragma unroll
            for (int ii = 0; ii < 8; ++ii) {                  // pads: +0 exact
                p0 = fmaf(A[ii].x, EC[4 * ii + 0], p0);
                p1 = fmaf(A[ii].y, EC[4 * ii + 1], p1);
                p2 = fmaf(A[ii].z, EC[4 * ii + 2], p2);
                p3 = fmaf(A[ii].w, EC[4 * ii + 3], p3);
            }
            anew = ((p0 + p1) + (p2 + p3)) * eemc;
            // refill (off critical chain)
            eemc = exp2f(fmaf(rawn, L2E, -5.0f));
            int tn = t + 2; tn = tn < NT ? tn : NT - 1;
            rawn = emS[tn * NK + jc];

            if ((t & 15) == 0) {       // exact pow2 renorm via lane-0 probe
                unsigned mb = (unsigned)__builtin_amdgcn_readfirstlane(
                                  __float_as_int(anew));
                int ex = (int)((mb >> 23) & 255u) - 127;
                anew *= __int_as_float((unsigned)(127 - ex) << 23);
                eshift += ex;
            }
            if (lane < 32) sA[lane] = (lane < NK) ? anew : 0.f;
        }
        float val = (lane < NK) ? anew * __expf(en[jc]) : 0.f;
#pragma unroll
        for (int s = 32; s; s >>= 1) val += __shfl_xor(val, s);
        float logZ = logf(val) + (float)eshift * LN2;
        const int* tg = tags + b * NT;
        float p = 0.f;
        for (int t = lane; t < NT; t += 64) {
            int tt = tg[t];
            p += emS[t * NK + tt];
            if (t == 0) p += st[tt];
            else        p += tr[tg[t - 1] * NK + tt];
            if (t == NT - 1) p += en[tt];
        }
#pragma unroll
        for (int s = 32; s; s >>= 1) p += __shfl_xor(p, s);
        if (lane == 0) part[b] = logZ - p;
    } else {
        // ----------------- Viterbi + parallel backtrace --------------------
        const int b = blockIdx.x - NB;
        const float* emb_b = em + (size_t)b * NT * NK;
        unsigned char* sbp = smem;                     // [511][32]
        unsigned char* smap = smem + 511 * 32;         // [16][32]

        float Tc[32];
#pragma unroll
        for (int i = 0; i < NK; ++i) Tc[i] = tr[i * NK + jc];
#pragma unroll
        for (int i = NK; i < 32; ++i) Tc[i] = 0.f;

        float sc = (lane < NK) ? (st[jc] + emb_b[jc]) : NEG_BIG;
        if (lane < 32) sA[lane] = (lane < NK) ? sc : NEG_BIG;

        float e0 = emb_b[1 * NK + jc];
        float e1 = emb_b[2 * NK + jc];
        float e2 = emb_b[3 * NK + jc];
        float e3 = emb_b[4 * NK + jc];

        auto vstep = [&](int t, float emt) {
            float4 q[8];
#pragma unroll
            for (int ii = 0; ii < 8; ++ii) q[ii] = sA4[ii];   // broadcast reads
            float v[32]; int id[32];
#pragma unroll
            for (int ii = 0; ii < 8; ++ii) {
                v[4 * ii + 0] = q[ii].x + Tc[4 * ii + 0];
                v[4 * ii + 1] = q[ii].y + Tc[4 * ii + 1];
                v[4 * ii + 2] = q[ii].z + Tc[4 * ii + 2];
                v[4 * ii + 3] = q[ii].w + Tc[4 * ii + 3];
            }
#pragma unroll
            for (int i = 0; i < 32; ++i) id[i] = i;
            // stable-left tournament => first-max (matches np.argmax)
#pragma unroll
            for (int w2 = 16; w2 >= 1; w2 >>= 1)
#pragma unroll
                for (int i = 0; i < 16; ++i) {
                    if (i < w2) {
                        bool g = v[i + w2] > v[i];
                        v[i] = g ? v[i + w2] : v[i];
                        id[i] = g ? id[i + w2] : id[i];
                    }
                }
            if (lane < 32) sbp[(t - 1) * 32 + lane] = (unsigned char)id[0];
            sc = (lane < NK) ? (v[0] + emt) : NEG_BIG;
            if (lane < 32) sA[lane] = (lane < NK) ? sc : NEG_BIG;
        };

        int t = 1;
        for (; t + 3 < NT; t += 4) {
            vstep(t + 0, e0); { int tn = t + 4; tn = tn < NT ? tn : NT - 1; e0 = emb_b[tn * NK + jc]; }
            vstep(t + 1, e1); { int tn = t + 5; tn = tn < NT ? tn : NT - 1; e1 = emb_b[tn * NK + jc]; }
            vstep(t + 2, e2); { int tn = t + 6; tn = tn < NT ? tn : NT - 1; e2 = emb_b[tn * NK + jc]; }
            vstep(t + 3, e3); { int tn = t + 7; tn = tn < NT ? tn : NT - 1; e3 = emb_b[tn * NK + jc]; }
        }
        vstep(509, e0); vstep(510, e1); vstep(511, e2);

        float v = (lane < NK) ? (sc + en[jc]) : NEG_BIG;
        float M = v;
#pragma unroll
        for (int s = 32; s; s >>= 1) M = fmaxf(M, __shfl_xor(M, s));
        unsigned long long mk = __ballot((lane < NK) && v == M);
        int last = (int)__builtin_ctzll(mk);

        // parallel backtrace: 16 segment maps of 32 rows, 8 per lane-half
        const int h = lane >> 5, j5 = lane & 31;
        int cur8[8];
#pragma unroll
        for (int rep = 0; rep < 8; ++rep) cur8[rep] = j5;
        for (int off = 0; off < 32; ++off) {
#pragma unroll
            for (int rep = 0; rep < 8; ++rep) {
                int s = 2 * rep + h;
                int hi = (s == 15) ? 511 : 32 * s + 32;
                int r = hi - 1 - off;
                if (r >= 32 * s) cur8[rep] = sbp[r * 32 + cur8[rep]];
            }
        }
#pragma unroll
        for (int rep = 0; rep < 8; ++rep)
            smap[(2 * rep + h) * 32 + j5] = (unsigned char)cur8[rep];

        int myhi = 0, cur = last;
        for (int s = 15; s >= 0; --s) {
            if (lane == s) myhi = cur;
            cur = smap[s * 32 + cur];
        }
        float* op = out + 1 + (size_t)b * NT;
        if (lane == 16) op[NT - 1] = (float)last;
        if (lane < 16) {
            int s = lane;
            int hi = (s == 15) ? 511 : 32 * s + 32;
            int c = myhi;
            for (int r = hi - 1; r >= 32 * s; --r) {
                c = sbp[r * 32 + c];
                op[r] = (float)c;
            }
        }
    }
}

// ---------------------------------------------------------------------------
// Kernel 3: nll = sum_b (logZ_b - num_b)
// ---------------------------------------------------------------------------
__global__ __launch_bounds__(64) void k_finish(const float* __restrict__ part,
                                               float* __restrict__ out)
{
    float v = part[threadIdx.x];
#pragma unroll
    for (int s = 32; s; s >>= 1) v += __shfl_xor(v, s);
    if (threadIdx.x == 0) out[0] = v;
}

extern "C" void kernel_launch(void* const* d_in, const int* in_sizes, int n_in,
                              void* d_out, int out_size, void* d_ws, size_t ws_size,
                              hipStream_t stream) {
    const int*   x    = (const int*)d_in[0];
    const int*   tags = (const int*)d_in[1];
    const float* emb  = (const float*)d_in[2];
    const float* w    = (const float*)d_in[3];
    const float* bias = (const float*)d_in[4];
    const float* st   = (const float*)d_in[5];
    const float* en   = (const float*)d_in[6];
    const float* tr   = (const float*)d_in[7];
    float* out = (float*)d_out;

    short* wbf  = (short*)d_ws;                              // 48 KB
    float* part = (float*)((char*)d_ws + 49152);             // 256 B
    float* em   = (float*)((char*)d_ws + 65536);             // 3.8 MB

    k_prep<<<96, 256, 0, stream>>>(w, wbf);
    k_emissions<<<2048, 128, 0, stream>>>(x, emb, wbf, bias, em);
    k_scan<<<2 * NB, 64, 0, stream>>>(em, tags, st, en, tr, part, out);
    k_finish<<<1, 64, 0, stream>>>(part, out);
}